// Round 10
// baseline (165.613 us; speedup 1.0000x reference)
//
#include <hip/hip_runtime.h>
#include <math.h>

#define N1 4096
#define N2 1024
#define C1 128
#define C2 256
#define CIN 384
#define H 256
#define BATCH 16
#define BN_EPS 1e-5f

typedef __attribute__((ext_vector_type(8))) short bf16x8;
typedef __attribute__((ext_vector_type(4))) float f32x4;

__device__ inline float bf2f(short s) {
    union { unsigned u; float f; } x;
    x.u = ((unsigned)(unsigned short)s) << 16;
    return x.f;
}
__device__ inline short f2bf(float f) {
    union { float f; unsigned u; } x; x.f = f;
    unsigned r = x.u + 0x7fffu + ((x.u >> 16) & 1u);
    return (short)(r >> 16);
}

typedef const __attribute__((address_space(1))) unsigned int guint;
typedef __attribute__((address_space(3))) unsigned int luint;
__device__ inline void gll16(const void* g, void* l) {
    __builtin_amdgcn_global_load_lds((guint*)g, (luint*)l, 16, 0, 0);
}

// ---------------- KNN: exact top-3 via min/med3 ----------------
__global__ __launch_bounds__(256)
void knn_kernel(const float* __restrict__ c1, const float* __restrict__ c2,
                float4* __restrict__ pk) {
    __shared__ __align__(16) float4 sc[N2];
    __shared__ float md[64 * 13];
    __shared__ int   mi[64 * 13];
    const int b = blockIdx.y;
    const float* c2b = c2 + (size_t)b * 3 * N2;
    for (int j = threadIdx.x; j < N2; j += 256) {
        float xx = c2b[j], yy = c2b[N2 + j], zz = c2b[2 * N2 + j];
        sc[j] = make_float4(xx, yy, zz, xx * xx + yy * yy + zz * zz);
    }
    __syncthreads();

    const int t = threadIdx.x;
    const int q = t & 63;
    const int quarter = t >> 6;
    const int n = blockIdx.x * 64 + q;
    const float* c1b = c1 + (size_t)b * 3 * N1;
    const float x = c1b[n], y = c1b[N1 + n], z = c1b[2 * N1 + n];
    const float s1 = x * x + y * y + z * z;

    float d0 = 3.4e38f, d1 = 3.4e38f, d2 = 3.4e38f;
    int i0 = 0, i1 = 0, i2 = 0;
    const int j0 = quarter * 256;
    #pragma unroll 8
    for (int jj = 0; jj < 256; ++jj) {
        const int j = j0 + jj;
        float4 cc = sc[j];
        float dot = x * cc.x + y * cc.y + z * cc.z;
        float d = s1 + cc.w - 2.0f * dot;
        bool c0v = d < d0, c1v = d < d1, c2v = d < d2;
        i2 = c1v ? i1 : (c2v ? j : i2);
        i1 = c0v ? i0 : (c1v ? j : i1);
        i0 = c0v ? j  : i0;
        d2 = __builtin_amdgcn_fmed3f(d1, d2, d);
        d1 = __builtin_amdgcn_fmed3f(d0, d1, d);
        d0 = fminf(d0, d);
    }
    const int mb = q * 13 + quarter * 3;
    md[mb + 0] = d0; md[mb + 1] = d1; md[mb + 2] = d2;
    mi[mb + 0] = i0; mi[mb + 1] = i1; mi[mb + 2] = i2;
    __syncthreads();

    if (t < 64) {
        float e0 = 3.4e38f, e1 = 3.4e38f, e2 = 3.4e38f;
        int a0 = 0, a1 = 0, a2 = 0;
        #pragma unroll
        for (int r = 0; r < 12; ++r) {
            const int rr = t * 13 + (r / 3) * 3 + (r % 3);
            float d = md[rr]; int j = mi[rr];
            bool c0 = d < e0, c1v = d < e1, c2v = d < e2;
            e2 = c1v ? e1 : (c2v ? d : e2);  a2 = c1v ? a1 : (c2v ? j : a2);
            e1 = c0 ? e0 : (c1v ? d : e1);   a1 = c0 ? a0 : (c1v ? j : a1);
            e0 = c0 ? d  : e0;               a0 = c0 ? j  : a0;
        }
        float r0 = 1.0f / (e0 + 1e-8f);
        float r1 = 1.0f / (e1 + 1e-8f);
        float r2 = 1.0f / (e2 + 1e-8f);
        float rs = r0 + r1 + r2;
        unsigned pack = (unsigned)a0 | ((unsigned)a1 << 10) | ((unsigned)a2 << 20);
        pk[(size_t)b * N1 + n] = make_float4(__uint_as_float(pack), r0 / rs, r1 / rs, r2 / rs);
    }
}

// ---------------- Prep: W [256][K] f32 -> swizzled bf16 [K/8][256][8] ----------------
__global__ __launch_bounds__(256)
void prep_w(const float* __restrict__ W, short* __restrict__ Wsw, int K) {
    const int nkb = K >> 3;
    const int id = blockIdx.x * 256 + threadIdx.x;
    if (id >= 256 * nkb) return;
    const int m = id / nkb, kb = id % nkb;
    const float* src = W + (size_t)m * K + kb * 8;
    bf16x8 v;
    #pragma unroll
    for (int j = 0; j < 8; ++j) v[j] = f2bf(src[j]);
    *(bf16x8*)(Wsw + ((size_t)kb * 256 + m) * 8) = v;
}

// ---------------- Transpose f2 [b][c][j] f32 -> f2t [b][j][c] bf16 ----------------
__global__ __launch_bounds__(256)
void transpose_f2(const float* __restrict__ f2, short* __restrict__ f2t) {
    __shared__ float st[32][33];
    const int j0 = blockIdx.x * 32, c0 = blockIdx.y * 32, b = blockIdx.z;
    const int t = threadIdx.x;
    {
        const int cc = t >> 3, jj = (t & 7) * 4;
        const float* src = f2 + ((size_t)b * C2 + c0 + cc) * N2 + j0 + jj;
        float4 v = *(const float4*)src;
        st[cc][jj + 0] = v.x; st[cc][jj + 1] = v.y;
        st[cc][jj + 2] = v.z; st[cc][jj + 3] = v.w;
    }
    __syncthreads();
    {
        const int j = t >> 3, cb = (t & 7) * 4;
        short4 v = { f2bf(st[cb + 0][j]), f2bf(st[cb + 1][j]),
                     f2bf(st[cb + 2][j]), f2bf(st[cb + 3][j]) };
        *(short4*)(f2t + ((size_t)b * N2 + j0 + j) * C2 + c0 + cb) = v;
    }
}

// ---------------- prep_B1: interp rows in kc layout [b][kb 0..31][n][8] ----------------
__global__ __launch_bounds__(256)
void prep_B1(const short* __restrict__ f2t, const float4* __restrict__ pk,
             short* __restrict__ B1) {
    const int b = blockIdx.y;
    const int n = blockIdx.x * 256 + threadIdx.x;
    float4 v = pk[(size_t)b * N1 + n];
    unsigned u = __float_as_uint(v.x);
    const short* r0 = f2t + ((size_t)b * N2 + (u & 1023u)) * C2;
    const short* r1 = f2t + ((size_t)b * N2 + ((u >> 10) & 1023u)) * C2;
    const short* r2 = f2t + ((size_t)b * N2 + ((u >> 20) & 1023u)) * C2;
    short* ob = B1 + ((size_t)b * 32 * N1 + n) * 8;
    #pragma unroll 4
    for (int kb = 0; kb < 32; ++kb) {
        bf16x8 g0 = *(const bf16x8*)(r0 + kb * 8);
        bf16x8 g1 = *(const bf16x8*)(r1 + kb * 8);
        bf16x8 g2 = *(const bf16x8*)(r2 + kb * 8);
        bf16x8 o;
        #pragma unroll
        for (int e = 0; e < 8; ++e)
            o[e] = f2bf(fmaf(v.w, bf2f(g2[e]), fmaf(v.z, bf2f(g1[e]), v.y * bf2f(g0[e]))));
        *(bf16x8*)(ob + (size_t)kb * N1 * 8) = o;
    }
}

// ---------------- m97-style MFMA GEMM: gll16 double-buffered LDS, 1 barrier/step ----------
// 128x128 tile, 256 threads / 4 waves (2m x 2n), wave tile 64x64.
// A: always gll16 from Wsw [K/8][256][8] (this block's mh half -> LDS [4][128][8]).
// B: MODE 0 steps 0-3 reg-staged from f1 (f32, T14 split); steps 4-11 gll16 from B1.
//    MODE 1: all 8 steps gll16 from y1r (post-BN bf16 kc layout).
// 1D grid 1024 pair-swizzled: mh-mates 8 apart -> same XCD L2 for shared B tile.
template<int MODE>
__global__ __launch_bounds__(256)
void gemm_kernel(const short* __restrict__ Wsw,
                 const float* __restrict__ f1, const short* __restrict__ Bkc,
                 short* __restrict__ Ykc, float2* __restrict__ P) {
    constexpr int K = (MODE == 0) ? CIN : H;
    constexpr int NT = K / 32;

    __shared__ __align__(16) short A_lds[2][4][128][8];  // 2 x 8KB
    __shared__ __align__(16) short B_lds[2][4][128][8];  // 2 x 8KB
    __shared__ float2 pb[128][2];

    const int t = threadIdx.x;
    const int d = blockIdx.x;
    const int grp = d >> 4, rem = d & 15;
    const int mh = rem >> 3;
    const int pair = grp * 8 + (rem & 7);
    const int nt = pair & 31, b = pair >> 5;
    const int n0 = nt * 128;

    const int lane = t & 63, wv = t >> 6;
    const int wm = wv >> 1, wn = wv & 1;
    const int l16 = lane & 15, lq = lane >> 4;

    const float* f1b = (MODE == 0) ? f1 + (size_t)b * C1 * N1 : (const float*)nullptr;
    const short* Bb = Bkc + (size_t)b * 32 * N1 * 8;

    const int skb = t >> 7;        // this thread's reg-stage chunks: skb, skb+2
    const int sn0 = t & 127;

    f32x4 acc[4][4];
    #pragma unroll
    for (int i = 0; i < 4; ++i)
        #pragma unroll
        for (int j = 0; j < 4; ++j)
            acc[i][j] = (f32x4){0.f, 0.f, 0.f, 0.f};

    auto stageA = [&](int step, int bufi) {
        #pragma unroll
        for (int i = 0; i < 2; ++i) {
            const int u0 = i * 256 + wv * 64;          // wave-uniform unit base
            const int kb = u0 >> 7, m0 = u0 & 127;
            const short* g = Wsw + (((size_t)step * 4 + kb) * 256 + mh * 128 + m0 + lane) * 8;
            gll16(g, &A_lds[bufi][0][0][0] + (size_t)u0 * 8);
        }
    };
    auto stageB_gll = [&](int kbg, int bufi) {         // B rows kbg..kbg+3 of kc buffer
        #pragma unroll
        for (int i = 0; i < 2; ++i) {
            const int u0 = i * 256 + wv * 64;
            const int kb = u0 >> 7, nn = u0 & 127;
            const short* g = Bb + (((size_t)(kbg + kb)) * N1 + n0 + nn + lane) * 8;
            gll16(g, &B_lds[bufi][0][0][0] + (size_t)u0 * 8);
        }
    };

    float pf[16];
    auto loadF1 = [&](int step) {
        #pragma unroll
        for (int h = 0; h < 2; ++h) {
            const int kb = skb + h * 2;
            const float* src = f1b + (size_t)(step * 32 + kb * 8) * N1 + n0 + sn0;
            #pragma unroll
            for (int e = 0; e < 8; ++e) pf[h * 8 + e] = src[(size_t)e * N1];
        }
    };
    auto writeF1 = [&](int bufi) {
        #pragma unroll
        for (int h = 0; h < 2; ++h) {
            const int kb = skb + h * 2;
            bf16x8 pv;
            #pragma unroll
            for (int e = 0; e < 8; ++e) pv[e] = f2bf(pf[h * 8 + e]);
            *(bf16x8*)&B_lds[bufi][kb][sn0][0] = pv;
        }
    };

    auto compute = [&](int bufi) {
        bf16x8 a[4], bb[4];
        #pragma unroll
        for (int f = 0; f < 4; ++f) {
            a[f]  = *(const bf16x8*)&A_lds[bufi][lq][wm * 64 + f * 16 + l16][0];
            bb[f] = *(const bf16x8*)&B_lds[bufi][lq][wn * 64 + f * 16 + l16][0];
        }
        #pragma unroll
        for (int i = 0; i < 4; ++i)
            #pragma unroll
            for (int j = 0; j < 4; ++j)
                acc[i][j] = __builtin_amdgcn_mfma_f32_16x16x32_bf16(a[i], bb[j], acc[i][j], 0, 0, 0);
    };

    // ---- prologue: tile 0 into buf 0 ----
    if (MODE == 0) {
        loadF1(0);
        stageA(0, 0);
        writeF1(0);
    } else {
        stageA(0, 0);
        stageB_gll(0, 0);
    }
    __syncthreads();   // drains vmcnt (gll) + lgkm (ds_write)

    int buf = 0;
    #pragma unroll
    for (int s = 0; s < NT; ++s) {
        const int sx = s + 1;
        const bool has_next = (sx < NT);
        const bool next_reg = (MODE == 0) && (sx < 4);
        if (has_next) {
            if (next_reg) loadF1(sx);
            stageA(sx, buf ^ 1);
            if (!next_reg) stageB_gll(MODE == 0 ? (sx * 4 - 16) : sx * 4, buf ^ 1);
        }
        compute(buf);
        if (has_next && next_reg) writeF1(buf ^ 1);
        __syncthreads();
        buf ^= 1;
    }

    // ---- epilogue: k-chunked store [kb][n][8] ----
    short* Yb = Ykc + (size_t)b * 32 * N1 * 8;
    #pragma unroll
    for (int i = 0; i < 4; ++i) {
        const int kb = mh * 16 + wm * 8 + i * 2 + (lq >> 1);
        const int kr0 = (lq & 1) * 4;
        #pragma unroll
        for (int j = 0; j < 4; ++j) {
            const int n = n0 + wn * 64 + j * 16 + l16;
            short4 v = { f2bf(acc[i][j][0]), f2bf(acc[i][j][1]),
                         f2bf(acc[i][j][2]), f2bf(acc[i][j][3]) };
            *(short4*)(Yb + ((size_t)kb * N1 + n) * 8 + kr0) = v;
        }
    }

    // ---- BN partials ----
    #pragma unroll
    for (int i = 0; i < 4; ++i) {
        #pragma unroll
        for (int r = 0; r < 4; ++r) {
            float s = 0.f, qq = 0.f;
            #pragma unroll
            for (int j = 0; j < 4; ++j) {
                float xv = acc[i][j][r];
                s += xv; qq += xv * xv;
            }
            #pragma unroll
            for (int msk = 1; msk < 16; msk <<= 1) {
                s  += __shfl_xor(s, msk);
                qq += __shfl_xor(qq, msk);
            }
            if (l16 == 0)
                pb[wm * 64 + i * 16 + lq * 4 + r][wn] = make_float2(s, qq);
        }
    }
    __syncthreads();
    if (t < 128) {
        float2 a = pb[t][0], c = pb[t][1];
        P[(size_t)(mh * 128 + t) * 512 + b * 32 + nt] = make_float2(a.x + c.x, a.y + c.y);
    }
}

// ---------------- BN reduce: partials [256][512] -> scale/shift ----------------
__global__ __launch_bounds__(256)
void bn_reduce(const float2* __restrict__ P, const float* __restrict__ g,
               const float* __restrict__ be, float* __restrict__ scale,
               float* __restrict__ shift) {
    const int c = blockIdx.x, t = threadIdx.x;
    float2 v0 = P[(size_t)c * 512 + t];
    float2 v1 = P[(size_t)c * 512 + 256 + t];
    float s = v0.x + v1.x, q = v0.y + v1.y;
    __shared__ float ss[256], sq[256];
    ss[t] = s; sq[t] = q;
    __syncthreads();
    for (int o = 128; o > 0; o >>= 1) {
        if (t < o) { ss[t] += ss[t + o]; sq[t] += sq[t + o]; }
        __syncthreads();
    }
    if (t == 0) {
        const float inv = 1.0f / (float)(BATCH * N1);
        float mean = ss[0] * inv;
        float var  = sq[0] * inv - mean * mean;
        float sc = g[c] / sqrtf(var + BN_EPS);
        scale[c] = sc;
        shift[c] = be[c] - mean * sc;
    }
}

// ---------------- bn_apply: y1kc -> y1r = relu(bn1(y1)) bf16, same kc layout ------------
__global__ __launch_bounds__(256)
void bn_apply(const short* __restrict__ yin, const float* __restrict__ scale,
              const float* __restrict__ shift, short* __restrict__ yout) {
    const int i8 = blockIdx.x * 256 + threadIdx.x;   // 2M bf16x8 units
    bf16x8 v = ((const bf16x8*)yin)[i8];
    const int c0 = ((i8 >> 12) & 31) * 8;            // 4096 units per kb row (FIX: >>12)
    bf16x8 o;
    #pragma unroll
    for (int e = 0; e < 8; ++e)
        o[e] = f2bf(fmaxf(fmaf(bf2f(v[e]), scale[c0 + e], shift[c0 + e]), 0.f));
    ((bf16x8*)yout)[i8] = o;
}

// ---------------- Final BN2+ReLU: y2kc -> f32 out (normal layout) ----------------
__global__ __launch_bounds__(256)
void final_bn_relu(const short* __restrict__ y2kc, const float* __restrict__ scale,
                   const float* __restrict__ shift, float* __restrict__ out) {
    const int t = threadIdx.x;
    const int n0 = blockIdx.x * 1024 + t * 4;
    const int kb = blockIdx.y, b = blockIdx.z;
    const short* src = y2kc + ((size_t)(b * 32 + kb) * N1 + n0) * 8;
    bf16x8 v0 = *(const bf16x8*)(src);
    bf16x8 v1 = *(const bf16x8*)(src + 8);
    bf16x8 v2 = *(const bf16x8*)(src + 16);
    bf16x8 v3 = *(const bf16x8*)(src + 24);
    #pragma unroll
    for (int e = 0; e < 8; ++e) {
        const float sc = scale[kb * 8 + e], sh = shift[kb * 8 + e];
        float4 o;
        o.x = fmaxf(fmaf(bf2f(v0[e]), sc, sh), 0.f);
        o.y = fmaxf(fmaf(bf2f(v1[e]), sc, sh), 0.f);
        o.z = fmaxf(fmaf(bf2f(v2[e]), sc, sh), 0.f);
        o.w = fmaxf(fmaf(bf2f(v3[e]), sc, sh), 0.f);
        *(float4*)(out + ((size_t)(b * 256 + kb * 8 + e) * N1) + n0) = o;
    }
}

extern "C" void kernel_launch(void* const* d_in, const int* in_sizes, int n_in,
                              void* d_out, int out_size, void* d_ws, size_t ws_size,
                              hipStream_t stream) {
    const float* c1  = (const float*)d_in[0];
    const float* c2  = (const float*)d_in[1];
    const float* f1  = (const float*)d_in[2];
    const float* f2  = (const float*)d_in[3];
    const float* W1  = (const float*)d_in[4];
    const float* g1  = (const float*)d_in[6];
    const float* be1 = (const float*)d_in[7];
    const float* W2  = (const float*)d_in[8];
    const float* g2  = (const float*)d_in[10];
    const float* be2 = (const float*)d_in[11];
    float* out = (float*)d_out;

    // ws regions (sequential-kernel overlap):
    // R1 [0,32MB):  B1 (prep_B1 -> gemm1), then y1r (bn_apply -> gemm2)
    // R2 [32,64MB): f2t (8MB, transpose -> prep_B1), then y1kc (gemm1 -> bn_apply),
    //               then y2kc (gemm2 -> final)
    // tail [64MB..): W1s | W2s | pk | P | scales
    char* ws = (char*)d_ws;
    short*  B1   = (short*)ws;
    short*  y1r  = (short*)ws;
    short*  f2t  = (short*)(ws + (32u << 20));
    short*  y1kc = (short*)(ws + (32u << 20));
    short*  y2kc = (short*)(ws + (32u << 20));
    short*  W1s  = (short*)(ws + (64u << 20));
    short*  W2s  = (short*)(ws + (64u << 20) + (256u << 10));
    float4* pk   = (float4*)(ws + (64u << 20) + (512u << 10));
    float2* P    = (float2*)(ws + (64u << 20) + (512u << 10) + (1u << 20));
    float* scale1 = (float*)(ws + (64u << 20) + (512u << 10) + (2u << 20));
    float* shift1 = scale1 + 256;
    float* scale2 = shift1 + 256;
    float* shift2 = scale2 + 256;

    prep_w<<<48, 256, 0, stream>>>(W1, W1s, CIN);
    prep_w<<<32, 256, 0, stream>>>(W2, W2s, H);
    transpose_f2<<<dim3(N2 / 32, C2 / 32, BATCH), 256, 0, stream>>>(f2, f2t);
    knn_kernel<<<dim3(N1 / 64, BATCH), 256, 0, stream>>>(c1, c2, pk);
    prep_B1<<<dim3(N1 / 256, BATCH), 256, 0, stream>>>(f2t, pk, B1);

    gemm_kernel<0><<<1024, 256, 0, stream>>>(W1s, f1, B1, y1kc, P);
    bn_reduce<<<256, 256, 0, stream>>>(P, g1, be1, scale1, shift1);
    bn_apply<<<8192, 256, 0, stream>>>(y1kc, scale1, shift1, y1r);

    gemm_kernel<1><<<1024, 256, 0, stream>>>(W2s, nullptr, y1r, y2kc, P);
    bn_reduce<<<256, 256, 0, stream>>>(P, g2, be2, scale2, shift2);

    final_bn_relu<<<dim3(N1 / 1024, 32, BATCH), 256, 0, stream>>>(y2kc, scale2, shift2, out);
}

// Round 11
// 155.370 us; speedup vs baseline: 1.0659x; 1.0659x over previous
//
#include <hip/hip_runtime.h>
#include <math.h>

#define N1 4096
#define N2 1024
#define C1 128
#define C2 256
#define CIN 384
#define H 256
#define BATCH 16
#define BN_EPS 1e-5f

typedef __attribute__((ext_vector_type(8))) short bf16x8;
typedef __attribute__((ext_vector_type(4))) float f32x4;

__device__ inline float bf2f(short s) {
    union { unsigned u; float f; } x;
    x.u = ((unsigned)(unsigned short)s) << 16;
    return x.f;
}
__device__ inline short f2bf(float f) {
    union { float f; unsigned u; } x; x.f = f;
    unsigned r = x.u + 0x7fffu + ((x.u >> 16) & 1u);
    return (short)(r >> 16);
}

typedef const __attribute__((address_space(1))) unsigned int guint;
typedef __attribute__((address_space(3))) unsigned int luint;
__device__ inline void gll16(const void* g, void* l) {
    __builtin_amdgcn_global_load_lds((guint*)g, (luint*)l, 16, 0, 0);
}

// ---------------- KNN: exact top-3 via min/med3 ----------------
__global__ __launch_bounds__(256)
void knn_kernel(const float* __restrict__ c1, const float* __restrict__ c2,
                float4* __restrict__ pk) {
    __shared__ __align__(16) float4 sc[N2];
    __shared__ float md[64 * 13];
    __shared__ int   mi[64 * 13];
    const int b = blockIdx.y;
    const float* c2b = c2 + (size_t)b * 3 * N2;
    for (int j = threadIdx.x; j < N2; j += 256) {
        float xx = c2b[j], yy = c2b[N2 + j], zz = c2b[2 * N2 + j];
        sc[j] = make_float4(xx, yy, zz, xx * xx + yy * yy + zz * zz);
    }
    __syncthreads();

    const int t = threadIdx.x;
    const int q = t & 63;
    const int quarter = t >> 6;
    const int n = blockIdx.x * 64 + q;
    const float* c1b = c1 + (size_t)b * 3 * N1;
    const float x = c1b[n], y = c1b[N1 + n], z = c1b[2 * N1 + n];
    const float s1 = x * x + y * y + z * z;

    float d0 = 3.4e38f, d1 = 3.4e38f, d2 = 3.4e38f;
    int i0 = 0, i1 = 0, i2 = 0;
    const int j0 = quarter * 256;
    #pragma unroll 8
    for (int jj = 0; jj < 256; ++jj) {
        const int j = j0 + jj;
        float4 cc = sc[j];
        float dot = x * cc.x + y * cc.y + z * cc.z;
        float d = s1 + cc.w - 2.0f * dot;
        bool c0v = d < d0, c1v = d < d1, c2v = d < d2;
        i2 = c1v ? i1 : (c2v ? j : i2);
        i1 = c0v ? i0 : (c1v ? j : i1);
        i0 = c0v ? j  : i0;
        d2 = __builtin_amdgcn_fmed3f(d1, d2, d);
        d1 = __builtin_amdgcn_fmed3f(d0, d1, d);
        d0 = fminf(d0, d);
    }
    const int mb = q * 13 + quarter * 3;
    md[mb + 0] = d0; md[mb + 1] = d1; md[mb + 2] = d2;
    mi[mb + 0] = i0; mi[mb + 1] = i1; mi[mb + 2] = i2;
    __syncthreads();

    if (t < 64) {
        float e0 = 3.4e38f, e1 = 3.4e38f, e2 = 3.4e38f;
        int a0 = 0, a1 = 0, a2 = 0;
        #pragma unroll
        for (int r = 0; r < 12; ++r) {
            const int rr = t * 13 + (r / 3) * 3 + (r % 3);
            float d = md[rr]; int j = mi[rr];
            bool c0 = d < e0, c1v = d < e1, c2v = d < e2;
            e2 = c1v ? e1 : (c2v ? d : e2);  a2 = c1v ? a1 : (c2v ? j : a2);
            e1 = c0 ? e0 : (c1v ? d : e1);   a1 = c0 ? a0 : (c1v ? j : a1);
            e0 = c0 ? d  : e0;               a0 = c0 ? j  : a0;
        }
        float r0 = 1.0f / (e0 + 1e-8f);
        float r1 = 1.0f / (e1 + 1e-8f);
        float r2 = 1.0f / (e2 + 1e-8f);
        float rs = r0 + r1 + r2;
        unsigned pack = (unsigned)a0 | ((unsigned)a1 << 10) | ((unsigned)a2 << 20);
        pk[(size_t)b * N1 + n] = make_float4(__uint_as_float(pack), r0 / rs, r1 / rs, r2 / rs);
    }
}

// ---------------- Prep: W [256][K] f32 -> swizzled bf16 [K/8][256][8] ----------------
__global__ __launch_bounds__(256)
void prep_w(const float* __restrict__ W, short* __restrict__ Wsw, int K) {
    const int nkb = K >> 3;
    const int id = blockIdx.x * 256 + threadIdx.x;
    if (id >= 256 * nkb) return;
    const int m = id / nkb, kb = id % nkb;
    const float* src = W + (size_t)m * K + kb * 8;
    bf16x8 v;
    #pragma unroll
    for (int j = 0; j < 8; ++j) v[j] = f2bf(src[j]);
    *(bf16x8*)(Wsw + ((size_t)kb * 256 + m) * 8) = v;
}

// ---------------- Transpose f2 [b][c][j] f32 -> f2t [b][j][c] bf16 ----------------
__global__ __launch_bounds__(256)
void transpose_f2(const float* __restrict__ f2, short* __restrict__ f2t) {
    __shared__ float st[32][33];
    const int j0 = blockIdx.x * 32, c0 = blockIdx.y * 32, b = blockIdx.z;
    const int t = threadIdx.x;
    {
        const int cc = t >> 3, jj = (t & 7) * 4;
        const float* src = f2 + ((size_t)b * C2 + c0 + cc) * N2 + j0 + jj;
        float4 v = *(const float4*)src;
        st[cc][jj + 0] = v.x; st[cc][jj + 1] = v.y;
        st[cc][jj + 2] = v.z; st[cc][jj + 3] = v.w;
    }
    __syncthreads();
    {
        const int j = t >> 3, cb = (t & 7) * 4;
        short4 v = { f2bf(st[cb + 0][j]), f2bf(st[cb + 1][j]),
                     f2bf(st[cb + 2][j]), f2bf(st[cb + 3][j]) };
        *(short4*)(f2t + ((size_t)b * N2 + j0 + j) * C2 + c0 + cb) = v;
    }
}

// ---------------- prep_B1: interp rows in kc layout [b][kb 0..31][n][8] ----------------
__global__ __launch_bounds__(256)
void prep_B1(const short* __restrict__ f2t, const float4* __restrict__ pk,
             short* __restrict__ B1) {
    const int b = blockIdx.y;
    const int n = blockIdx.x * 256 + threadIdx.x;
    float4 v = pk[(size_t)b * N1 + n];
    unsigned u = __float_as_uint(v.x);
    const short* r0 = f2t + ((size_t)b * N2 + (u & 1023u)) * C2;
    const short* r1 = f2t + ((size_t)b * N2 + ((u >> 10) & 1023u)) * C2;
    const short* r2 = f2t + ((size_t)b * N2 + ((u >> 20) & 1023u)) * C2;
    short* ob = B1 + ((size_t)b * 32 * N1 + n) * 8;
    #pragma unroll 4
    for (int kb = 0; kb < 32; ++kb) {
        bf16x8 g0 = *(const bf16x8*)(r0 + kb * 8);
        bf16x8 g1 = *(const bf16x8*)(r1 + kb * 8);
        bf16x8 g2 = *(const bf16x8*)(r2 + kb * 8);
        bf16x8 o;
        #pragma unroll
        for (int e = 0; e < 8; ++e)
            o[e] = f2bf(fmaf(v.w, bf2f(g2[e]), fmaf(v.z, bf2f(g1[e]), v.y * bf2f(g0[e]))));
        *(bf16x8*)(ob + (size_t)kb * N1 * 8) = o;
    }
}

// ---------------- Pipelined MFMA GEMM (T4): 3-buffer, counted vmcnt, raw barriers --------
// 128x128 tile, 256 threads / 4 waves. 2 staging steps in flight across barriers
// (never vmcnt(0) mid-loop). NT=12: steps 0-3 B from f1 (f32 reg path, order-pinned
// issue; counted waits keep gll16 FIFO math exact); steps 4-11 gll16 from B1.
// NT=8 (BN=true): all steps gll16 from y1kc; BN1+ReLU applied on fragment read.
template<int NT, bool BN>
__global__ __launch_bounds__(256)
void gemm_kernel(const short* __restrict__ Wsw,
                 const float* __restrict__ f1, const short* __restrict__ Bkc,
                 const float* __restrict__ scale, const float* __restrict__ shift,
                 short* __restrict__ Ykc, float2* __restrict__ P) {
    constexpr bool M0 = (NT == 12);

    __shared__ __align__(16) short A_lds[3][4][128][8];  // 24KB
    __shared__ __align__(16) short B_lds[3][4][128][8];  // 24KB
    __shared__ float sc_s[256], sh_s[256];
    __shared__ float2 pb[128][2];

    const int t = threadIdx.x;
    const int d = blockIdx.x;
    const int grp = d >> 4, rem = d & 15;
    const int mh = rem >> 3;
    const int pair = grp * 8 + (rem & 7);
    const int nt = pair & 31, b = pair >> 5;
    const int n0 = nt * 128;

    const int lane = t & 63, wv = t >> 6;
    const int wm = wv >> 1, wn = wv & 1;
    const int l16 = lane & 15, lq = lane >> 4;

    if (BN) {
        sc_s[t] = scale[t]; sh_s[t] = shift[t];
        __syncthreads();
    }

    const float* f1b = M0 ? (f1 + (size_t)b * C1 * N1) : (const float*)nullptr;
    const short* Bb = Bkc + (size_t)b * 32 * N1 * 8;
    const int skb = t >> 7, sn0 = t & 127;

    f32x4 acc[4][4];
    #pragma unroll
    for (int i = 0; i < 4; ++i)
        #pragma unroll
        for (int j = 0; j < 4; ++j)
            acc[i][j] = (f32x4){0.f, 0.f, 0.f, 0.f};

    auto stageA = [&](int step, int bufi) {
        #pragma unroll
        for (int i = 0; i < 2; ++i) {
            const int u0 = i * 256 + wv * 64;
            const int kb = u0 >> 7, m0 = u0 & 127;
            const short* g = Wsw + (((size_t)step * 4 + kb) * 256 + mh * 128 + m0 + lane) * 8;
            gll16(g, &A_lds[bufi][0][0][0] + (size_t)u0 * 8);
        }
    };
    auto stageB = [&](int step, int bufi) {
        const int kbg = M0 ? (step * 4 - 16) : step * 4;
        #pragma unroll
        for (int i = 0; i < 2; ++i) {
            const int u0 = i * 256 + wv * 64;
            const int kb = u0 >> 7, nn = u0 & 127;
            const short* g = Bb + (((size_t)(kbg + kb)) * N1 + n0 + nn + lane) * 8;
            gll16(g, &B_lds[bufi][0][0][0] + (size_t)u0 * 8);
        }
    };
    auto issueF1 = [&](int step, float* pf) {
        #pragma unroll
        for (int h = 0; h < 2; ++h) {
            const int kb = skb + h * 2;
            const float* src = f1b + (size_t)(step * 32 + kb * 8) * N1 + n0 + sn0;
            #pragma unroll
            for (int e = 0; e < 8; ++e) pf[h * 8 + e] = src[(size_t)e * N1];
        }
    };
    auto commitF1 = [&](const float* pf, int bufi) {
        #pragma unroll
        for (int h = 0; h < 2; ++h) {
            bf16x8 pv;
            #pragma unroll
            for (int e = 0; e < 8; ++e) pv[e] = f2bf(pf[h * 8 + e]);
            *(bf16x8*)&B_lds[bufi][skb + h * 2][sn0][0] = pv;
        }
    };
    auto compute = [&](int bufi, int s) {
        bf16x8 a[4], bb[4];
        #pragma unroll
        for (int f = 0; f < 4; ++f)
            a[f] = *(const bf16x8*)&A_lds[bufi][lq][wm * 64 + f * 16 + l16][0];
        if (BN) {
            float sck[8], shk[8];
            const int k0 = s * 32 + lq * 8;
            #pragma unroll
            for (int e = 0; e < 8; ++e) { sck[e] = sc_s[k0 + e]; shk[e] = sh_s[k0 + e]; }
            #pragma unroll
            for (int f = 0; f < 4; ++f) {
                bf16x8 raw = *(const bf16x8*)&B_lds[bufi][lq][wn * 64 + f * 16 + l16][0];
                #pragma unroll
                for (int e = 0; e < 8; ++e)
                    bb[f][e] = f2bf(fmaxf(fmaf(bf2f(raw[e]), sck[e], shk[e]), 0.f));
            }
        } else {
            #pragma unroll
            for (int f = 0; f < 4; ++f)
                bb[f] = *(const bf16x8*)&B_lds[bufi][lq][wn * 64 + f * 16 + l16][0];
        }
        #pragma unroll
        for (int i = 0; i < 4; ++i)
            #pragma unroll
            for (int j = 0; j < 4; ++j)
                acc[i][j] = __builtin_amdgcn_mfma_f32_16x16x32_bf16(a[i], bb[j], acc[i][j], 0, 0, 0);
    };

    float pfA[16], pfB[16];

    // ---- prologue: 2 steps in flight ----
    if (M0) {
        issueF1(0, pfA); __builtin_amdgcn_sched_barrier(0);
        stageA(0, 0);    __builtin_amdgcn_sched_barrier(0);
        issueF1(1, pfB); __builtin_amdgcn_sched_barrier(0);
        stageA(1, 1);    __builtin_amdgcn_sched_barrier(0);
        asm volatile("s_waitcnt vmcnt(2) lgkmcnt(0)" ::: "memory");
        __builtin_amdgcn_sched_barrier(0);
        commitF1(pfA, 0);
    } else {
        stageA(0, 0); stageB(0, 0);
        stageA(1, 1); stageB(1, 1);
    }

    #pragma unroll
    for (int s = 0; s < NT; ++s) {
        // counted wait: step-s staging complete; step-(s+1) loads stay in flight
        if (M0 && s + 1 < 4)
            asm volatile("s_waitcnt vmcnt(2) lgkmcnt(0)" ::: "memory");
        else if (s == NT - 1)
            asm volatile("s_waitcnt vmcnt(0) lgkmcnt(0)" ::: "memory");
        else
            asm volatile("s_waitcnt vmcnt(4) lgkmcnt(0)" ::: "memory");
        __builtin_amdgcn_sched_barrier(0);
        __builtin_amdgcn_s_barrier();
        __builtin_amdgcn_sched_barrier(0);

        const int st = s + 2;
        if (st < NT) {
            if (M0 && st < 4) {
                if (st & 1) issueF1(st, pfB); else issueF1(st, pfA);
                __builtin_amdgcn_sched_barrier(0);
                stageA(st, st % 3);
            } else {
                stageA(st, st % 3);
                stageB(st, st % 3);
            }
        }
        if (M0 && s + 1 < 4) {
            if ((s + 1) & 1) commitF1(pfB, (s + 1) % 3);
            else             commitF1(pfA, (s + 1) % 3);
        }
        compute(s % 3, s);
    }

    // ---- epilogue: k-chunked store [kb][n][8] ----
    short* Yb = Ykc + (size_t)b * 32 * N1 * 8;
    #pragma unroll
    for (int i = 0; i < 4; ++i) {
        const int kb = mh * 16 + wm * 8 + i * 2 + (lq >> 1);
        const int kr0 = (lq & 1) * 4;
        #pragma unroll
        for (int j = 0; j < 4; ++j) {
            const int n = n0 + wn * 64 + j * 16 + l16;
            short4 v = { f2bf(acc[i][j][0]), f2bf(acc[i][j][1]),
                         f2bf(acc[i][j][2]), f2bf(acc[i][j][3]) };
            *(short4*)(Yb + ((size_t)kb * N1 + n) * 8 + kr0) = v;
        }
    }

    // ---- BN partials ----
    #pragma unroll
    for (int i = 0; i < 4; ++i) {
        #pragma unroll
        for (int r = 0; r < 4; ++r) {
            float s = 0.f, qq = 0.f;
            #pragma unroll
            for (int j = 0; j < 4; ++j) {
                float xv = acc[i][j][r];
                s += xv; qq += xv * xv;
            }
            #pragma unroll
            for (int msk = 1; msk < 16; msk <<= 1) {
                s  += __shfl_xor(s, msk);
                qq += __shfl_xor(qq, msk);
            }
            if (l16 == 0)
                pb[wm * 64 + i * 16 + lq * 4 + r][wn] = make_float2(s, qq);
        }
    }
    __syncthreads();
    if (t < 128) {
        float2 a = pb[t][0], c = pb[t][1];
        P[(size_t)(mh * 128 + t) * 512 + b * 32 + nt] = make_float2(a.x + c.x, a.y + c.y);
    }
}

// ---------------- BN reduce: partials [256][512] -> scale/shift ----------------
__global__ __launch_bounds__(256)
void bn_reduce(const float2* __restrict__ P, const float* __restrict__ g,
               const float* __restrict__ be, float* __restrict__ scale,
               float* __restrict__ shift) {
    const int c = blockIdx.x, t = threadIdx.x;
    float2 v0 = P[(size_t)c * 512 + t];
    float2 v1 = P[(size_t)c * 512 + 256 + t];
    float s = v0.x + v1.x, q = v0.y + v1.y;
    __shared__ float ss[256], sq[256];
    ss[t] = s; sq[t] = q;
    __syncthreads();
    for (int o = 128; o > 0; o >>= 1) {
        if (t < o) { ss[t] += ss[t + o]; sq[t] += sq[t + o]; }
        __syncthreads();
    }
    if (t == 0) {
        const float inv = 1.0f / (float)(BATCH * N1);
        float mean = ss[0] * inv;
        float var  = sq[0] * inv - mean * mean;
        float sc = g[c] / sqrtf(var + BN_EPS);
        scale[c] = sc;
        shift[c] = be[c] - mean * sc;
    }
}

// ---------------- Final BN2+ReLU: y2kc -> f32 out (normal layout) ----------------
__global__ __launch_bounds__(256)
void final_bn_relu(const short* __restrict__ y2kc, const float* __restrict__ scale,
                   const float* __restrict__ shift, float* __restrict__ out) {
    const int t = threadIdx.x;
    const int n0 = blockIdx.x * 1024 + t * 4;
    const int kb = blockIdx.y, b = blockIdx.z;
    const short* src = y2kc + ((size_t)(b * 32 + kb) * N1 + n0) * 8;
    bf16x8 v0 = *(const bf16x8*)(src);
    bf16x8 v1 = *(const bf16x8*)(src + 8);
    bf16x8 v2 = *(const bf16x8*)(src + 16);
    bf16x8 v3 = *(const bf16x8*)(src + 24);
    #pragma unroll
    for (int e = 0; e < 8; ++e) {
        const float sc = scale[kb * 8 + e], sh = shift[kb * 8 + e];
        float4 o;
        o.x = fmaxf(fmaf(bf2f(v0[e]), sc, sh), 0.f);
        o.y = fmaxf(fmaf(bf2f(v1[e]), sc, sh), 0.f);
        o.z = fmaxf(fmaf(bf2f(v2[e]), sc, sh), 0.f);
        o.w = fmaxf(fmaf(bf2f(v3[e]), sc, sh), 0.f);
        *(float4*)(out + ((size_t)(b * 256 + kb * 8 + e) * N1) + n0) = o;
    }
}

extern "C" void kernel_launch(void* const* d_in, const int* in_sizes, int n_in,
                              void* d_out, int out_size, void* d_ws, size_t ws_size,
                              hipStream_t stream) {
    const float* c1  = (const float*)d_in[0];
    const float* c2  = (const float*)d_in[1];
    const float* f1  = (const float*)d_in[2];
    const float* f2  = (const float*)d_in[3];
    const float* W1  = (const float*)d_in[4];
    const float* g1  = (const float*)d_in[6];
    const float* be1 = (const float*)d_in[7];
    const float* W2  = (const float*)d_in[8];
    const float* g2  = (const float*)d_in[10];
    const float* be2 = (const float*)d_in[11];
    float* out = (float*)d_out;

    // ws regions (sequential-kernel overlap, peak 66.5 MiB):
    // [0,32 MiB):  B1 (prep_B1 -> gemm1), then y2kc (gemm2 -> final)
    // [32,64):     f2t (8 MiB, transpose -> prep_B1), then y1kc (gemm1 -> gemm2)
    // [64..):      W1s | W2s | pk | P | scales
    char* ws = (char*)d_ws;
    short*  B1   = (short*)ws;
    short*  y2kc = (short*)ws;
    short*  f2t  = (short*)(ws + (32u << 20));
    short*  y1kc = (short*)(ws + (32u << 20));
    short*  W1s  = (short*)(ws + (64u << 20));
    short*  W2s  = (short*)(ws + (64u << 20) + (256u << 10));
    float4* pk   = (float4*)(ws + (64u << 20) + (512u << 10));
    float2* P    = (float2*)(ws + (64u << 20) + (512u << 10) + (1u << 20));
    float* scale1 = (float*)(ws + (64u << 20) + (512u << 10) + (2u << 20));
    float* shift1 = scale1 + 256;
    float* scale2 = shift1 + 256;
    float* shift2 = scale2 + 256;

    prep_w<<<48, 256, 0, stream>>>(W1, W1s, CIN);
    prep_w<<<32, 256, 0, stream>>>(W2, W2s, H);
    transpose_f2<<<dim3(N2 / 32, C2 / 32, BATCH), 256, 0, stream>>>(f2, f2t);
    knn_kernel<<<dim3(N1 / 64, BATCH), 256, 0, stream>>>(c1, c2, pk);
    prep_B1<<<dim3(N1 / 256, BATCH), 256, 0, stream>>>(f2t, pk, B1);

    gemm_kernel<12, false><<<1024, 256, 0, stream>>>(
        W1s, f1, B1, nullptr, nullptr, y1kc, P);
    bn_reduce<<<256, 256, 0, stream>>>(P, g1, be1, scale1, shift1);

    gemm_kernel<8, true><<<1024, 256, 0, stream>>>(
        W2s, nullptr, y1kc, scale1, shift1, y2kc, P);
    bn_reduce<<<256, 256, 0, stream>>>(P, g2, be2, scale2, shift2);

    final_bn_relu<<<dim3(N1 / 1024, 32, BATCH), 256, 0, stream>>>(y2kc, scale2, shift2, out);
}